// Round 14
// baseline (317.114 us; speedup 1.0000x reference)
//
#include <hip/hip_runtime.h>
#include <hip/hip_fp16.h>
#include <math.h>

#define T_TOW 4
#define F_DIM 32
#define H_DIM 128

typedef _Float16 half2_t __attribute__((ext_vector_type(2)));

#if defined(__has_builtin)
#if __has_builtin(__builtin_amdgcn_fdot2)
#define HAVE_FDOT2 1
#endif
#endif

static __device__ __forceinline__ float fdot2_acc(half2_t a, half2_t b, float c) {
#ifdef HAVE_FDOT2
    return __builtin_amdgcn_fdot2(a, b, c, false);
#else
    return c + (float)a.x * (float)b.x + (float)a.y * (float)b.y;
#endif
}

static __device__ __forceinline__ half2_t u2h(unsigned u) {
    union { unsigned u; half2_t h; } x; x.u = u; return x.h;
}
static __device__ __forceinline__ unsigned h2u(float a, float b) {
    union { half2_t h; unsigned u; } x;
    x.h.x = (_Float16)a; x.h.y = (_Float16)b; return x.u;
}

// ---------------- K1: fused prep: ctab/avg_log (block 0) + transposes + count
// w1q layout: [q][lane] uint4, q=0..7; lane = channel-pair (c0=2*lane,c1=c0+1).
//   q<4:  uint4 = A-row pairs j=4q..4q+3   (pair j = (w1[c0][2j], w1[c0][2j+1]))
//   q>=4: uint4 = B-row pairs j=4(q-4)..   (from row c1)
__global__ void k_prep(const float* __restrict__ emb, const float* __restrict__ edge_w,
                       const float* __restrict__ edge_b, const float* __restrict__ pre_w0,
                       const float* __restrict__ pre_b0, const float* __restrict__ pre_w1,
                       const int* __restrict__ deg_hist,
                       const float* __restrict__ post_w0, const float* __restrict__ post_w1,
                       const float* __restrict__ lin_w, const int* __restrict__ dst, int E,
                       float* __restrict__ ctab, float* __restrict__ scal,
                       unsigned* __restrict__ W3h, float* __restrict__ w1t,
                       float* __restrict__ lwt, float* __restrict__ wab,
                       unsigned* __restrict__ w1q, int* __restrict__ cnt) {
    int i = blockIdx.x * blockDim.x + threadIdx.x;
    // --- block 0: edge-encoder table + avg_log ---
    if (blockIdx.x == 0) {
        __shared__ float e_sh[5 * 32];
        int tid = threadIdx.x;
        for (int j = tid; j < 5 * 32; j += blockDim.x) {
            int b = j >> 5, f = j & 31;
            float acc = edge_b[f];
            const float* er = emb + b * 128;
            const float* wr = edge_w + f * 128;
            for (int k = 0; k < 128; ++k) acc += er[k] * wr[k];
            e_sh[j] = acc;
        }
        __syncthreads();
        for (int j = tid; j < 5 * 128; j += blockDim.x) {
            int b = j >> 7, c = j & 127;
            float acc = pre_b0[c];
            const float* w = pre_w0 + c * 96 + 64;
            const float* e = e_sh + b * 32;
            for (int f = 0; f < 32; ++f) acc += w[f] * e[f];
            ctab[j] = acc;
        }
        if (tid == 0) {
            float num = 0.f, den = 0.f;
            for (int j = 0; j < 17; ++j) {
                float d = (float)deg_hist[j];
                num += logf((float)(j + 1)) * d;
                den += d;
            }
            scal[0] = num / den;
        }
    }
    // --- W3h: packed post_w0 V-form, 4*3*96*32 = 36864 ---
    if (i < T_TOW * 3 * 96 * 32) {
        int t = i / (3 * 96 * 32);
        int r = i % (3 * 96 * 32);
        int p = r / (96 * 32);
        int r2 = r % (96 * 32);
        int k2 = r2 >> 5, g = r2 & 31;
        const float* row = post_w0 + (size_t)(t * 32 + g) * 512;
        float v0, v1;
        int k0 = 2 * k2, k1 = 2 * k2 + 1;
        if (p == 0) { v0 = row[k0]; v1 = row[k1]; }
        else {
            v0 = (k0 >= 32) ? row[p * 160 + k0] : 0.f;
            v1 = (k1 >= 32) ? row[p * 160 + k1] : 0.f;
        }
        W3h[i] = h2u(v0, v1);
    }
    if (i < T_TOW * F_DIM * F_DIM) {   // post_w1 [t][g][f] -> w1t [t][f][g]
        int t = i >> 10;
        int r = i & 1023;
        int g = r >> 5, f = r & 31;
        w1t[(t * 32 + f) * 32 + g] = post_w1[i];
    }
    if (i < H_DIM * H_DIM) {           // lin_w [j][k] -> lwt [k][j]
        int j = i >> 7, k = i & 127;
        lwt[k * H_DIM + j] = lin_w[i];
    }
    if (i < 2 * T_TOW * F_DIM * F_DIM) { // wab[s][t][f][g] = pre_w0[t*32+g][s*32+f]
        int s = i >> 12;
        int r = i & 4095;
        int t = r >> 10;
        int r2 = r & 1023;
        int f = r2 >> 5, g = r2 & 31;
        wab[i] = pre_w0[(size_t)(t * 32 + g) * 96 + s * 32 + f];
    }
    if (i < 2048) {                    // w1q packed pre_w1 (coalesced lane layout)
        int q = i >> 8;                // 0..7
        int lane = (i >> 2) & 63;
        int s = i & 3;
        int j = (q < 4) ? 4 * q + s : 4 * (q - 4) + s;
        int c = (q < 4) ? 2 * lane : 2 * lane + 1;
        w1q[i] = h2u(pre_w1[c * 32 + 2 * j], pre_w1[c * 32 + 2 * j + 1]);
    }
    // --- in-degree count (grid-stride) ---
    for (int e = i; e < E; e += gridDim.x * blockDim.x) atomicAdd(&cnt[dst[e]], 1);
}

// ---------------- K2: single-block full scan (cnt -> rs, cur) --------------
__global__ __launch_bounds__(1024) void k_scan_all(const int* __restrict__ cnt,
                                                   int* __restrict__ rs,
                                                   int* __restrict__ cur, int n) {
    __shared__ int sh[1024];
    int tid = threadIdx.x;
    int chunk = (n + 1023) >> 10;
    int c0 = tid * chunk, c1 = min(c0 + chunk, n);
    int s = 0;
    for (int j = c0; j < c1; ++j) s += cnt[j];
    sh[tid] = s;
    __syncthreads();
    for (int off = 1; off < 1024; off <<= 1) {
        int u = (tid >= off) ? sh[tid - off] : 0;
        __syncthreads();
        sh[tid] += u;
        __syncthreads();
    }
    int run = sh[tid] - s;
    for (int j = c0; j < c1; ++j) {
        rs[j] = run; cur[j] = run;
        run += cnt[j];
    }
    if (tid == 1023) rs[n] = sh[1023];
}

// ---------------- K3: bucket edges by dst ----------------
__global__ void k_bucket(const int* __restrict__ src, const int* __restrict__ dst,
                         const int* __restrict__ bond, int* __restrict__ cur,
                         int* __restrict__ srcS, int* __restrict__ bndS, int E) {
    int e = blockIdx.x * blockDim.x + threadIdx.x;
    if (e < E) {
        int d = dst[e];
        int slot = atomicAdd(&cur[d], 1);
        srcS[slot] = src[e];
        bndS[slot] = bond[e];
    }
}

// ---------------- K4: per-node A (f32) / B (f16) via V-form ---------------
__global__ __launch_bounds__(256) void k_ab3(
    const float* __restrict__ x, const float* __restrict__ wab,
    float* __restrict__ A, _Float16* __restrict__ Bh, int n) {
    __shared__ float xt[64 * 133];
    int tid = threadIdx.x;
    int base = blockIdx.x * 64;
    for (int i = tid; i < 2048; i += 256) {
        int nl = i >> 5, q = i & 31;
        int node = min(base + nl, n - 1);
        float4 v = *(const float4*)(x + (size_t)node * 128 + q * 4);
        float* d = xt + nl * 133 + q * 4;
        d[0] = v.x; d[1] = v.y; d[2] = v.z; d[3] = v.w;
    }
    __syncthreads();
    int t = __builtin_amdgcn_readfirstlane(tid >> 6);
    int lane = tid & 63;
    float accA[32], accB[32];
#pragma unroll
    for (int g = 0; g < 32; ++g) { accA[g] = 0.f; accB[g] = 0.f; }
    const float* xs = xt + lane * 133 + t * 32;
    const float* wa = wab + (size_t)t * 1024;              // [f][g]
    const float* wb = wab + 4096 + (size_t)t * 1024;
    for (int f = 0; f < 32; ++f) {
        float v = xs[f];
#pragma unroll
        for (int g = 0; g < 32; ++g) {
            accA[g] += wa[g] * v;
            accB[g] += wb[g] * v;
        }
        wa += 32; wb += 32;
    }
    int node = base + lane;
    if (node < n) {
        float* ar = A + (size_t)node * 128 + t * 32;
#pragma unroll
        for (int q = 0; q < 8; ++q)
            *(float4*)(ar + q * 4) = make_float4(accA[q * 4], accA[q * 4 + 1], accA[q * 4 + 2], accA[q * 4 + 3]);
        _Float16* br = Bh + (size_t)node * 128 + t * 32;
#pragma unroll
        for (int q = 0; q < 4; ++q) {
            uint4 u;
            u.x = h2u(accB[8 * q + 0], accB[8 * q + 1]);
            u.y = h2u(accB[8 * q + 2], accB[8 * q + 3]);
            u.z = h2u(accB[8 * q + 4], accB[8 * q + 5]);
            u.w = h2u(accB[8 * q + 6], accB[8 * q + 7]);
            *(uint4*)(br + q * 8) = u;
        }
    }
}

// ---------------- K5: edge aggregation, f16 dot2, high occupancy -----------
// No LDS weight staging: each lane loads its 8 coalesced uint4 from w1q.
// LDS = cbuf 2.5KB + pbuf 1KB -> launch_bounds(256,8) = 32 waves/CU.
__global__ __launch_bounds__(256, 8) void k_edge8(
    const float* __restrict__ A, const _Float16* __restrict__ Bh,
    const float* __restrict__ ctab, const unsigned* __restrict__ w1q,
    const float* __restrict__ pre_b1, const int* __restrict__ rs,
    const int* __restrict__ srcS, const int* __restrict__ bndS,
    float* __restrict__ stats, int n) {
    __shared__ float cbuf[640];          // 2.5 KB
    __shared__ unsigned pbuf[4][64];     // [wave][t*16+i16] packed half2 (1 KB)
    int tid = threadIdx.x;
    for (int i = tid; i < 640; i += 256) cbuf[i] = ctab[i];
    __syncthreads();

    int w = tid >> 6;
    int lane = tid & 63;
    int node = blockIdx.x * 4 + w;
    if (node >= n) return;
    int c0 = lane * 2;
    int t = lane >> 4;                 // tower
    int i16 = lane & 15;

    half2_t wpa[16], wpb[16];
    {
        const uint4* wq = (const uint4*)w1q;
#pragma unroll
        for (int q = 0; q < 4; ++q) {
            uint4 v = wq[q * 64 + lane];
            wpa[4 * q + 0] = u2h(v.x); wpa[4 * q + 1] = u2h(v.y);
            wpa[4 * q + 2] = u2h(v.z); wpa[4 * q + 3] = u2h(v.w);
        }
#pragma unroll
        for (int q = 0; q < 4; ++q) {
            uint4 v = wq[(q + 4) * 64 + lane];
            wpb[4 * q + 0] = u2h(v.x); wpb[4 * q + 1] = u2h(v.y);
            wpb[4 * q + 2] = u2h(v.z); wpb[4 * q + 3] = u2h(v.w);
        }
    }
    float b1a = pre_b1[c0], b1b = pre_b1[c0 + 1];
    float2 av = ((const float2*)(A + (size_t)node * H_DIM))[lane];
    const uint4* pk4 = (const uint4*)&pbuf[w][t * 16];
    unsigned* pslot = &pbuf[w][t * 16 + i16];

    int e0 = rs[node], e1 = rs[node + 1];
    float sum0 = 0.f, sum1 = 0.f, sq0 = 0.f, sq1 = 0.f;
    float mn0 = INFINITY, mn1 = INFINITY, mx0 = -INFINITY, mx1 = -INFINITY;

    half2_t b2_n; b2_n.x = (_Float16)0.f; b2_n.y = (_Float16)0.f;
    float2 c2_n = make_float2(0.f, 0.f);
    if (e0 < e1) {
        int sv = srcS[e0];
        int bv = bndS[e0];
        b2_n = ((const half2_t*)(Bh + (size_t)sv * H_DIM))[lane];
        c2_n = ((const float2*)(cbuf + bv * 128))[lane];
    }
    for (int e = e0; e < e1; ++e) {
        half2_t b2 = b2_n;
        float2 c2 = c2_n;
        if (e + 1 < e1) {
            int sv = srcS[e + 1];
            int bv = bndS[e + 1];
            b2_n = ((const half2_t*)(Bh + (size_t)sv * H_DIM))[lane];
            c2_n = ((const float2*)(cbuf + bv * 128))[lane];
        }
        float p0 = fmaxf(av.x + (float)b2.x + c2.x, 0.f);
        float p1 = fmaxf(av.y + (float)b2.y + c2.y, 0.f);
        *pslot = h2u(p0, p1);
        float hx = b1a, hy = b1b;
#pragma unroll
        for (int q = 0; q < 4; ++q) {
            uint4 v = pk4[q];
            hx = fdot2_acc(wpa[4 * q + 0], u2h(v.x), hx);
            hy = fdot2_acc(wpb[4 * q + 0], u2h(v.x), hy);
            hx = fdot2_acc(wpa[4 * q + 1], u2h(v.y), hx);
            hy = fdot2_acc(wpb[4 * q + 1], u2h(v.y), hy);
            hx = fdot2_acc(wpa[4 * q + 2], u2h(v.z), hx);
            hy = fdot2_acc(wpb[4 * q + 2], u2h(v.z), hy);
            hx = fdot2_acc(wpa[4 * q + 3], u2h(v.w), hx);
            hy = fdot2_acc(wpb[4 * q + 3], u2h(v.w), hy);
        }
        sum0 += hx; sum1 += hy;
        sq0 += hx * hx; sq1 += hy * hy;
        mn0 = fminf(mn0, hx); mn1 = fminf(mn1, hy);
        mx0 = fmaxf(mx0, hx); mx1 = fmaxf(mx1, hy);
    }
    if (e1 <= e0) { mn0 = mn1 = mx0 = mx1 = 0.f; }
    float2* st2 = (float2*)(stats + (size_t)node * 512);
    st2[lane]        = make_float2(sum0, sum1);
    st2[64 + lane]   = make_float2(sq0, sq1);
    st2[128 + lane]  = make_float2(mn0, mn1);
    st2[192 + lane]  = make_float2(mx0, mx1);
}

// ---------------- K6: post-MLP, packed-f16 dot2 V-form ---------------------
__global__ __launch_bounds__(192) void k_post5(
    const float* __restrict__ x, const float* __restrict__ stats,
    const int* __restrict__ rs, const float* __restrict__ scal,
    const unsigned* __restrict__ W3h, const float* __restrict__ w1t,
    const float* __restrict__ post_b0, const float* __restrict__ post_b1,
    __half* __restrict__ y1, int n) {
    __shared__ __align__(16) char smraw[64 * 194 * 2];   // 24832 B
    __half* uh = (__half*)smraw;                         // [node][194]
    __half* zh = (__half*)smraw;                         // [p][64][34]
    __half* rh = (__half*)(smraw + 3 * 64 * 34 * 2);     // [64][34]
    int bid = blockIdx.x;
    int tile = bid >> 2, t = bid & 3;
    int tid = threadIdx.x;
    int p = __builtin_amdgcn_readfirstlane(tid >> 6);
    int lane = tid & 63;
    int base = tile * 64;

    for (int i = tid; i < 512; i += 192) {
        int nl = i >> 3, q = i & 7;
        int node = min(base + nl, n - 1);
        float4 v = *(const float4*)(x + (size_t)node * 128 + t * 32 + q * 4);
        __half* d = uh + nl * 194 + q * 4;
        d[0] = __float2half(v.x); d[1] = __float2half(v.y);
        d[2] = __float2half(v.z); d[3] = __float2half(v.w);
    }
    for (int i = tid; i < 512; i += 192) {
        int nl = i >> 3, q = i & 7;
        int node = min(base + nl, n - 1);
        int cnt = rs[node + 1] - rs[node];
        float inv = 1.f / fmaxf((float)cnt, 1.f);
        const float* sp = stats + (size_t)node * 512 + t * 32 + q * 4;
        float4 s4  = *(const float4*)(sp);
        float4 q4  = *(const float4*)(sp + 128);
        float4 mn4 = *(const float4*)(sp + 256);
        float4 mx4 = *(const float4*)(sp + 384);
        float me[4] = { s4.x * inv, s4.y * inv, s4.z * inv, s4.w * inv };
        float qq[4] = { q4.x, q4.y, q4.z, q4.w };
        __half* d = uh + nl * 194 + q * 4;
        d[32] = __float2half(s4.x);  d[33] = __float2half(s4.y);
        d[34] = __float2half(s4.z);  d[35] = __float2half(s4.w);
#pragma unroll
        for (int j = 0; j < 4; ++j) {
            d[64 + j] = __float2half(me[j]);
            d[160 + j] = __float2half(sqrtf(fmaxf(qq[j] * inv - me[j] * me[j], 0.f) + 1e-5f));
        }
        d[96] = __float2half(mn4.x);  d[97] = __float2half(mn4.y);
        d[98] = __float2half(mn4.z);  d[99] = __float2half(mn4.w);
        d[128] = __float2half(mx4.x); d[129] = __float2half(mx4.y);
        d[130] = __float2half(mx4.z); d[131] = __float2half(mx4.w);
    }
    __syncthreads();

    float acc[32];
#pragma unroll
    for (int g = 0; g < 32; ++g) acc[g] = 0.f;
    int k20 = (p == 0) ? 0 : 16;
    const unsigned* wrow = W3h + ((size_t)(t * 3 + p) * 96 + k20) * 32;
    const unsigned* us2 = (const unsigned*)(uh + lane * 194);
    for (int k2 = k20; k2 < 96; ++k2) {
        half2_t uv = u2h(us2[k2]);
#pragma unroll
        for (int g = 0; g < 32; ++g) acc[g] = fdot2_acc(u2h(wrow[g]), uv, acc[g]);
        wrow += 32;
    }
    __syncthreads();
    {
        __half* zb = zh + p * (64 * 34) + lane * 34;
#pragma unroll
        for (int g = 0; g < 32; ++g) zb[g] = __float2half(acc[g]);
    }
    __syncthreads();
    if (tid < 64) {
        int nodec = min(base + tid, n - 1);
        int cnt = rs[nodec + 1] - rs[nodec];
        float cnt1 = fmaxf((float)cnt, 1.f);
        float logd = logf(cnt1 + 1.f);
        float avg = scal[0];
        float s1 = logd / avg, s2 = avg / logd;
        const float* b0 = post_b0 + t * 32;
        const __half* z0 = zh + tid * 34;
        const __half* z1 = zh + 64 * 34 + tid * 34;
        const __half* z2 = zh + 2 * 64 * 34 + tid * 34;
        __half* rb = rh + tid * 34;
#pragma unroll
        for (int g = 0; g < 32; ++g) {
            float r = __half2float(z0[g]) + s1 * __half2float(z1[g]) + s2 * __half2float(z2[g]) + b0[g];
            rb[g] = __float2half(fmaxf(r, 0.f));
        }
    }
    __syncthreads();
    if (tid < 128) {
        int h = __builtin_amdgcn_readfirstlane(tid >> 6);
        int l = tid & 63;
        float acc2[16];
        const float* b1 = post_b1 + t * 32 + h * 16;
#pragma unroll
        for (int j = 0; j < 16; ++j) acc2[j] = b1[j];
        const __half* rb = rh + l * 34;
        const float* w1 = w1t + (t * 32) * 32 + h * 16;
#pragma unroll
        for (int f = 0; f < 32; ++f) {
            float rv = __half2float(rb[f]);
#pragma unroll
            for (int j = 0; j < 16; ++j) acc2[j] += w1[f * 32 + j] * rv;
        }
        int node2 = base + l;
        if (node2 < n) {
            __half* yr = y1 + (size_t)node2 * 128 + t * 32 + h * 16;
#pragma unroll
            for (int j = 0; j < 16; ++j) yr[j] = __float2half(acc2[j]);
        }
    }
}

// ---------------- K7: Linear(128,128) + LN + ReLU + residual ---------------
__global__ __launch_bounds__(256) void k_final3(
    const __half* __restrict__ y1, const float* __restrict__ lwt,
    const float* __restrict__ lin_b, const float* __restrict__ ln_g,
    const float* __restrict__ ln_b, const float* __restrict__ x,
    float* __restrict__ out, int n) {
    __shared__ __half yt[64 * 130];
    __shared__ float lnbuf[64][8];
    int tid = threadIdx.x;
    int base = blockIdx.x * 64;
    for (int i = tid; i < 1024; i += 256) {
        int nl = i >> 4, q = i & 15;
        int node = min(base + nl, n - 1);
        const __half* sp = y1 + (size_t)node * 128 + q * 8;
        __half* d = yt + nl * 130 + q * 8;
#pragma unroll
        for (int j = 0; j < 8; ++j) d[j] = sp[j];
    }
    __syncthreads();
    int w = __builtin_amdgcn_readfirstlane(tid >> 6);
    int l = tid & 63;
    int j0 = w * 32;
    float acc[32];
    const float* lb = lin_b + j0;
#pragma unroll
    for (int j = 0; j < 32; ++j) acc[j] = lb[j];
    const __half* yrow = yt + l * 130;
    const float* wr = lwt + j0;
    for (int k = 0; k < 128; ++k) {
        float v = __half2float(yrow[k]);
#pragma unroll
        for (int j = 0; j < 32; ++j) acc[j] += wr[j] * v;
        wr += 128;
    }
    float s = 0.f, sq = 0.f;
#pragma unroll
    for (int j = 0; j < 32; ++j) { s += acc[j]; sq += acc[j] * acc[j]; }
    lnbuf[l][w * 2] = s;
    lnbuf[l][w * 2 + 1] = sq;
    __syncthreads();
    float S = 0.f, SQ = 0.f;
#pragma unroll
    for (int i = 0; i < 4; ++i) { S += lnbuf[l][2 * i]; SQ += lnbuf[l][2 * i + 1]; }
    float mu = S * (1.f / 128.f);
    float var = fmaxf(SQ * (1.f / 128.f) - mu * mu, 0.f);
    float rstd = rsqrtf(var + 1e-5f);
    int node = base + l;
    if (node < n) {
        const float* xr = x + (size_t)node * 128 + j0;
        float* orow = out + (size_t)node * 128 + j0;
#pragma unroll
        for (int j = 0; j < 32; ++j) {
            float o = (acc[j] - mu) * rstd * ln_g[j0 + j] + ln_b[j0 + j];
            orow[j] = xr[j] + fmaxf(o, 0.f);
        }
    }
}

extern "C" void kernel_launch(void* const* d_in, const int* in_sizes, int n_in,
                              void* d_out, int out_size, void* d_ws, size_t ws_size,
                              hipStream_t stream) {
    const float* atom_x   = (const float*)d_in[0];
    const int*   bond_x   = (const int*)d_in[1];
    const int*   aei      = (const int*)d_in[2];
    const int*   deg_hist = (const int*)d_in[3];
    const float* emb      = (const float*)d_in[4];
    const float* edge_w   = (const float*)d_in[5];
    const float* edge_b   = (const float*)d_in[6];
    const float* pre_w0   = (const float*)d_in[7];
    const float* pre_b0   = (const float*)d_in[8];
    const float* pre_w1   = (const float*)d_in[9];
    const float* pre_b1   = (const float*)d_in[10];
    const float* post_w0  = (const float*)d_in[11];
    const float* post_b0  = (const float*)d_in[12];
    const float* post_w1  = (const float*)d_in[13];
    const float* post_b1  = (const float*)d_in[14];
    const float* lin_w    = (const float*)d_in[15];
    const float* lin_b    = (const float*)d_in[16];
    const float* ln_g     = (const float*)d_in[17];
    const float* ln_b     = (const float*)d_in[18];

    int n = in_sizes[0] / H_DIM;     // 40000
    int E = in_sizes[1];             // 320000
    const int* src = aei;
    const int* dst = aei + E;

    char* ws = (char*)d_ws;
    size_t off = 0;
    auto alloc = [&](size_t bytes) {
        size_t r = off;
        off = (off + bytes + 511) & ~(size_t)511;
        return r;
    };
    float*    ctab  = (float*)(ws + alloc(5 * 128 * 4));
    float*    scal  = (float*)(ws + alloc(256));
    unsigned* W3h   = (unsigned*)(ws + alloc((size_t)4 * 3 * 96 * 32 * 4));
    float*    w1t   = (float*)(ws + alloc(4 * 32 * 32 * 4));
    float*    lwt   = (float*)(ws + alloc(128 * 128 * 4));
    float*    wab   = (float*)(ws + alloc(2 * 4 * 32 * 32 * 4));
    unsigned* w1q   = (unsigned*)(ws + alloc(2048 * 4));
    int*      cnt   = (int*)(ws + alloc((size_t)n * 4));
    int*      rs    = (int*)(ws + alloc((size_t)(n + 1) * 4));
    int*      cur   = (int*)(ws + alloc((size_t)n * 4));
    int*      srcS  = (int*)(ws + alloc((size_t)E * 4));
    int*      bndS  = (int*)(ws + alloc((size_t)E * 4));
    float*    A     = (float*)(ws + alloc((size_t)n * 128 * 4));
    _Float16* Bh    = (_Float16*)(ws + alloc((size_t)n * 128 * 2));
    float*    stats = (float*)(ws + alloc((size_t)n * 512 * 4));
    __half*   y1    = (__half*)A;   // A dead after k_edge8

    if (off > ws_size) return;

    hipMemsetAsync(cnt, 0, (size_t)n * 4, stream);
    int nPrep = (T_TOW * 3 * 96 * 32 + 255) / 256;   // 144 blocks covers all branches
    k_prep<<<nPrep, 256, 0, stream>>>(emb, edge_w, edge_b, pre_w0, pre_b0, pre_w1, deg_hist,
                                      post_w0, post_w1, lin_w, dst, E,
                                      ctab, scal, W3h, w1t, lwt, wab, w1q, cnt);
    k_scan_all<<<1, 1024, 0, stream>>>(cnt, rs, cur, n);
    k_bucket<<<(E + 255) / 256, 256, 0, stream>>>(src, dst, bond_x, cur, srcS, bndS, E);
    int nTiles = (n + 63) / 64;
    k_ab3<<<nTiles, 256, 0, stream>>>(atom_x, wab, A, Bh, n);
    k_edge8<<<(n + 3) / 4, 256, 0, stream>>>(A, Bh, ctab, w1q, pre_b1, rs, srcS, bndS,
                                             stats, n);
    k_post5<<<nTiles * 4, 192, 0, stream>>>(atom_x, stats, rs, scal, W3h, w1t,
                                            post_b0, post_b1, y1, n);
    k_final3<<<nTiles, 256, 0, stream>>>(y1, lwt, lin_b, ln_g, ln_b, atom_x,
                                         (float*)d_out, n);
}

// Round 15
// 236.124 us; speedup vs baseline: 1.3430x; 1.3430x over previous
//
#include <hip/hip_runtime.h>
#include <hip/hip_fp16.h>
#include <math.h>

#define T_TOW 4
#define F_DIM 32
#define H_DIM 128

typedef _Float16 half2_t __attribute__((ext_vector_type(2)));

#if defined(__has_builtin)
#if __has_builtin(__builtin_amdgcn_fdot2)
#define HAVE_FDOT2 1
#endif
#endif

static __device__ __forceinline__ float fdot2_acc(half2_t a, half2_t b, float c) {
#ifdef HAVE_FDOT2
    return __builtin_amdgcn_fdot2(a, b, c, false);
#else
    return c + (float)a.x * (float)b.x + (float)a.y * (float)b.y;
#endif
}

static __device__ __forceinline__ half2_t u2h(unsigned u) {
    union { unsigned u; half2_t h; } x; x.u = u; return x.h;
}
static __device__ __forceinline__ unsigned h2u(float a, float b) {
    union { half2_t h; unsigned u; } x;
    x.h.x = (_Float16)a; x.h.y = (_Float16)b; return x.u;
}

// ---------------- K1: fused prep: ctab/avg_log (block 0) + transposes + count
__global__ void k_prep(const float* __restrict__ emb, const float* __restrict__ edge_w,
                       const float* __restrict__ edge_b, const float* __restrict__ pre_w0,
                       const float* __restrict__ pre_b0, const float* __restrict__ pre_w1,
                       const int* __restrict__ deg_hist,
                       const float* __restrict__ post_w0, const float* __restrict__ post_w1,
                       const float* __restrict__ lin_w, const int* __restrict__ dst, int E,
                       float* __restrict__ ctab, float* __restrict__ scal,
                       unsigned* __restrict__ W3h, float* __restrict__ w1t,
                       float* __restrict__ lwt, float* __restrict__ wab,
                       unsigned* __restrict__ w1q, int* __restrict__ cnt) {
    int i = blockIdx.x * blockDim.x + threadIdx.x;
    if (blockIdx.x == 0) {
        __shared__ float e_sh[5 * 32];
        int tid = threadIdx.x;
        for (int j = tid; j < 5 * 32; j += blockDim.x) {
            int b = j >> 5, f = j & 31;
            float acc = edge_b[f];
            const float* er = emb + b * 128;
            const float* wr = edge_w + f * 128;
            for (int k = 0; k < 128; ++k) acc += er[k] * wr[k];
            e_sh[j] = acc;
        }
        __syncthreads();
        for (int j = tid; j < 5 * 128; j += blockDim.x) {
            int b = j >> 7, c = j & 127;
            float acc = pre_b0[c];
            const float* w = pre_w0 + c * 96 + 64;
            const float* e = e_sh + b * 32;
            for (int f = 0; f < 32; ++f) acc += w[f] * e[f];
            ctab[j] = acc;
        }
        if (tid == 0) {
            float num = 0.f, den = 0.f;
            for (int j = 0; j < 17; ++j) {
                float d = (float)deg_hist[j];
                num += logf((float)(j + 1)) * d;
                den += d;
            }
            scal[0] = num / den;
        }
    }
    if (i < T_TOW * 3 * 96 * 32) {
        int t = i / (3 * 96 * 32);
        int r = i % (3 * 96 * 32);
        int p = r / (96 * 32);
        int r2 = r % (96 * 32);
        int k2 = r2 >> 5, g = r2 & 31;
        const float* row = post_w0 + (size_t)(t * 32 + g) * 512;
        float v0, v1;
        int k0 = 2 * k2, k1 = 2 * k2 + 1;
        if (p == 0) { v0 = row[k0]; v1 = row[k1]; }
        else {
            v0 = (k0 >= 32) ? row[p * 160 + k0] : 0.f;
            v1 = (k1 >= 32) ? row[p * 160 + k1] : 0.f;
        }
        W3h[i] = h2u(v0, v1);
    }
    if (i < T_TOW * F_DIM * F_DIM) {   // post_w1 [t][g][f] -> w1t [t][f][g]
        int t = i >> 10;
        int r = i & 1023;
        int g = r >> 5, f = r & 31;
        w1t[(t * 32 + f) * 32 + g] = post_w1[i];
    }
    if (i < H_DIM * H_DIM) {           // lin_w [j][k] -> lwt [k][j]
        int j = i >> 7, k = i & 127;
        lwt[k * H_DIM + j] = lin_w[i];
    }
    if (i < 2 * T_TOW * F_DIM * F_DIM) { // wab[s][t][f][g] = pre_w0[t*32+g][s*32+f]
        int s = i >> 12;
        int r = i & 4095;
        int t = r >> 10;
        int r2 = r & 1023;
        int f = r2 >> 5, g = r2 & 31;
        wab[i] = pre_w0[(size_t)(t * 32 + g) * 96 + s * 32 + f];
    }
    if (i < 2048) {                    // w1q packed pre_w1 (coalesced lane layout)
        int q = i >> 8;
        int lane = (i >> 2) & 63;
        int s = i & 3;
        int j = (q < 4) ? 4 * q + s : 4 * (q - 4) + s;
        int c = (q < 4) ? 2 * lane : 2 * lane + 1;
        w1q[i] = h2u(pre_w1[c * 32 + 2 * j], pre_w1[c * 32 + 2 * j + 1]);
    }
    for (int e = i; e < E; e += gridDim.x * blockDim.x) atomicAdd(&cnt[dst[e]], 1);
}

// ---------------- K2: hierarchical exclusive scan (3 kernels) --------------
__global__ void k_blocksum(const int* __restrict__ cnt, int* __restrict__ bsum, int n) {
    __shared__ int sh[256];
    int i = blockIdx.x * 256 + threadIdx.x;
    sh[threadIdx.x] = (i < n) ? cnt[i] : 0;
    __syncthreads();
    for (int off = 128; off > 0; off >>= 1) {
        if (threadIdx.x < off) sh[threadIdx.x] += sh[threadIdx.x + off];
        __syncthreads();
    }
    if (threadIdx.x == 0) bsum[blockIdx.x] = sh[0];
}

__global__ void k_scanb(const int* __restrict__ bsum, int* __restrict__ boff, int nb,
                        int* __restrict__ rs, int n_nodes) {
    __shared__ int sh[512];
    int tid = threadIdx.x;
    int v = (tid < nb) ? bsum[tid] : 0;
    sh[tid] = v;
    __syncthreads();
    for (int off = 1; off < 512; off <<= 1) {
        int u = (tid >= off) ? sh[tid - off] : 0;
        __syncthreads();
        sh[tid] += u;
        __syncthreads();
    }
    if (tid < nb) boff[tid] = sh[tid] - v;
    if (tid == 511) rs[n_nodes] = sh[511];
}

__global__ void k_scanc(const int* __restrict__ cnt, const int* __restrict__ boff,
                        int* __restrict__ rs, int* __restrict__ cur, int n) {
    __shared__ int sh[256];
    int i = blockIdx.x * 256 + threadIdx.x;
    int v = (i < n) ? cnt[i] : 0;
    sh[threadIdx.x] = v;
    __syncthreads();
    for (int off = 1; off < 256; off <<= 1) {
        int u = (threadIdx.x >= off) ? sh[threadIdx.x - off] : 0;
        __syncthreads();
        sh[threadIdx.x] += u;
        __syncthreads();
    }
    if (i < n) {
        int excl = sh[threadIdx.x] - v + boff[blockIdx.x];
        rs[i] = excl;
        cur[i] = excl;
    }
}

// ---------------- K3: bucket edges by dst ----------------
__global__ void k_bucket(const int* __restrict__ src, const int* __restrict__ dst,
                         const int* __restrict__ bond, int* __restrict__ cur,
                         int* __restrict__ srcS, int* __restrict__ bndS, int E) {
    int e = blockIdx.x * blockDim.x + threadIdx.x;
    if (e < E) {
        int d = dst[e];
        int slot = atomicAdd(&cur[d], 1);
        srcS[slot] = src[e];
        bndS[slot] = bond[e];
    }
}

// ---------------- K4: per-node A (f32) / B (f16) via V-form ---------------
__global__ __launch_bounds__(256) void k_ab3(
    const float* __restrict__ x, const float* __restrict__ wab,
    float* __restrict__ A, _Float16* __restrict__ Bh, int n) {
    __shared__ float xt[64 * 133];
    int tid = threadIdx.x;
    int base = blockIdx.x * 64;
    for (int i = tid; i < 2048; i += 256) {
        int nl = i >> 5, q = i & 31;
        int node = min(base + nl, n - 1);
        float4 v = *(const float4*)(x + (size_t)node * 128 + q * 4);
        float* d = xt + nl * 133 + q * 4;
        d[0] = v.x; d[1] = v.y; d[2] = v.z; d[3] = v.w;
    }
    __syncthreads();
    int t = __builtin_amdgcn_readfirstlane(tid >> 6);
    int lane = tid & 63;
    float accA[32], accB[32];
#pragma unroll
    for (int g = 0; g < 32; ++g) { accA[g] = 0.f; accB[g] = 0.f; }
    const float* xs = xt + lane * 133 + t * 32;
    const float* wa = wab + (size_t)t * 1024;              // [f][g]
    const float* wb = wab + 4096 + (size_t)t * 1024;
    for (int f = 0; f < 32; ++f) {
        float v = xs[f];
#pragma unroll
        for (int g = 0; g < 32; ++g) {
            accA[g] += wa[g] * v;
            accB[g] += wb[g] * v;
        }
        wa += 32; wb += 32;
    }
    int node = base + lane;
    if (node < n) {
        float* ar = A + (size_t)node * 128 + t * 32;
#pragma unroll
        for (int q = 0; q < 8; ++q)
            *(float4*)(ar + q * 4) = make_float4(accA[q * 4], accA[q * 4 + 1], accA[q * 4 + 2], accA[q * 4 + 3]);
        _Float16* br = Bh + (size_t)node * 128 + t * 32;
#pragma unroll
        for (int q = 0; q < 4; ++q) {
            uint4 u;
            u.x = h2u(accB[8 * q + 0], accB[8 * q + 1]);
            u.y = h2u(accB[8 * q + 2], accB[8 * q + 3]);
            u.z = h2u(accB[8 * q + 4], accB[8 * q + 5]);
            u.w = h2u(accB[8 * q + 6], accB[8 * q + 7]);
            *(uint4*)(br + q * 8) = u;
        }
    }
}

// ---------------- K5: edge aggregation, f16 dot2, high occupancy -----------
__global__ __launch_bounds__(256, 8) void k_edge8(
    const float* __restrict__ A, const _Float16* __restrict__ Bh,
    const float* __restrict__ ctab, const unsigned* __restrict__ w1q,
    const float* __restrict__ pre_b1, const int* __restrict__ rs,
    const int* __restrict__ srcS, const int* __restrict__ bndS,
    float* __restrict__ stats, int n) {
    __shared__ float cbuf[640];          // 2.5 KB
    __shared__ unsigned pbuf[4][64];     // [wave][t*16+i16] packed half2 (1 KB)
    int tid = threadIdx.x;
    for (int i = tid; i < 640; i += 256) cbuf[i] = ctab[i];
    __syncthreads();

    int w = tid >> 6;
    int lane = tid & 63;
    int node = blockIdx.x * 4 + w;
    if (node >= n) return;
    int c0 = lane * 2;
    int t = lane >> 4;                 // tower
    int i16 = lane & 15;

    half2_t wpa[16], wpb[16];
    {
        const uint4* wq = (const uint4*)w1q;
#pragma unroll
        for (int q = 0; q < 4; ++q) {
            uint4 v = wq[q * 64 + lane];
            wpa[4 * q + 0] = u2h(v.x); wpa[4 * q + 1] = u2h(v.y);
            wpa[4 * q + 2] = u2h(v.z); wpa[4 * q + 3] = u2h(v.w);
        }
#pragma unroll
        for (int q = 0; q < 4; ++q) {
            uint4 v = wq[(q + 4) * 64 + lane];
            wpb[4 * q + 0] = u2h(v.x); wpb[4 * q + 1] = u2h(v.y);
            wpb[4 * q + 2] = u2h(v.z); wpb[4 * q + 3] = u2h(v.w);
        }
    }
    float b1a = pre_b1[c0], b1b = pre_b1[c0 + 1];
    float2 av = ((const float2*)(A + (size_t)node * H_DIM))[lane];
    const uint4* pk4 = (const uint4*)&pbuf[w][t * 16];
    unsigned* pslot = &pbuf[w][t * 16 + i16];

    int e0 = rs[node], e1 = rs[node + 1];
    float sum0 = 0.f, sum1 = 0.f, sq0 = 0.f, sq1 = 0.f;
    float mn0 = INFINITY, mn1 = INFINITY, mx0 = -INFINITY, mx1 = -INFINITY;

    half2_t b2_n; b2_n.x = (_Float16)0.f; b2_n.y = (_Float16)0.f;
    float2 c2_n = make_float2(0.f, 0.f);
    if (e0 < e1) {
        int sv = srcS[e0];
        int bv = bndS[e0];
        b2_n = ((const half2_t*)(Bh + (size_t)sv * H_DIM))[lane];
        c2_n = ((const float2*)(cbuf + bv * 128))[lane];
    }
    for (int e = e0; e < e1; ++e) {
        half2_t b2 = b2_n;
        float2 c2 = c2_n;
        if (e + 1 < e1) {
            int sv = srcS[e + 1];
            int bv = bndS[e + 1];
            b2_n = ((const half2_t*)(Bh + (size_t)sv * H_DIM))[lane];
            c2_n = ((const float2*)(cbuf + bv * 128))[lane];
        }
        float p0 = fmaxf(av.x + (float)b2.x + c2.x, 0.f);
        float p1 = fmaxf(av.y + (float)b2.y + c2.y, 0.f);
        *pslot = h2u(p0, p1);
        float hx = b1a, hy = b1b;
#pragma unroll
        for (int q = 0; q < 4; ++q) {
            uint4 v = pk4[q];
            hx = fdot2_acc(wpa[4 * q + 0], u2h(v.x), hx);
            hy = fdot2_acc(wpb[4 * q + 0], u2h(v.x), hy);
            hx = fdot2_acc(wpa[4 * q + 1], u2h(v.y), hx);
            hy = fdot2_acc(wpb[4 * q + 1], u2h(v.y), hy);
            hx = fdot2_acc(wpa[4 * q + 2], u2h(v.z), hx);
            hy = fdot2_acc(wpb[4 * q + 2], u2h(v.z), hy);
            hx = fdot2_acc(wpa[4 * q + 3], u2h(v.w), hx);
            hy = fdot2_acc(wpb[4 * q + 3], u2h(v.w), hy);
        }
        sum0 += hx; sum1 += hy;
        sq0 += hx * hx; sq1 += hy * hy;
        mn0 = fminf(mn0, hx); mn1 = fminf(mn1, hy);
        mx0 = fmaxf(mx0, hx); mx1 = fmaxf(mx1, hy);
    }
    if (e1 <= e0) { mn0 = mn1 = mx0 = mx1 = 0.f; }
    float2* st2 = (float2*)(stats + (size_t)node * 512);
    st2[lane]        = make_float2(sum0, sum1);
    st2[64 + lane]   = make_float2(sq0, sq1);
    st2[128 + lane]  = make_float2(mn0, mn1);
    st2[192 + lane]  = make_float2(mx0, mx1);
}

// ---------------- K6: post-MLP, packed-f16 dot2 V-form ---------------------
__global__ __launch_bounds__(192) void k_post5(
    const float* __restrict__ x, const float* __restrict__ stats,
    const int* __restrict__ rs, const float* __restrict__ scal,
    const unsigned* __restrict__ W3h, const float* __restrict__ w1t,
    const float* __restrict__ post_b0, const float* __restrict__ post_b1,
    __half* __restrict__ y1, int n) {
    __shared__ __align__(16) char smraw[64 * 194 * 2];   // 24832 B
    __half* uh = (__half*)smraw;                         // [node][194]
    __half* zh = (__half*)smraw;                         // [p][64][34]
    __half* rh = (__half*)(smraw + 3 * 64 * 34 * 2);     // [64][34]
    int bid = blockIdx.x;
    int tile = bid >> 2, t = bid & 3;
    int tid = threadIdx.x;
    int p = __builtin_amdgcn_readfirstlane(tid >> 6);
    int lane = tid & 63;
    int base = tile * 64;

    for (int i = tid; i < 512; i += 192) {
        int nl = i >> 3, q = i & 7;
        int node = min(base + nl, n - 1);
        float4 v = *(const float4*)(x + (size_t)node * 128 + t * 32 + q * 4);
        __half* d = uh + nl * 194 + q * 4;
        d[0] = __float2half(v.x); d[1] = __float2half(v.y);
        d[2] = __float2half(v.z); d[3] = __float2half(v.w);
    }
    for (int i = tid; i < 512; i += 192) {
        int nl = i >> 3, q = i & 7;
        int node = min(base + nl, n - 1);
        int cnt = rs[node + 1] - rs[node];
        float inv = 1.f / fmaxf((float)cnt, 1.f);
        const float* sp = stats + (size_t)node * 512 + t * 32 + q * 4;
        float4 s4  = *(const float4*)(sp);
        float4 q4  = *(const float4*)(sp + 128);
        float4 mn4 = *(const float4*)(sp + 256);
        float4 mx4 = *(const float4*)(sp + 384);
        float me[4] = { s4.x * inv, s4.y * inv, s4.z * inv, s4.w * inv };
        float qq[4] = { q4.x, q4.y, q4.z, q4.w };
        __half* d = uh + nl * 194 + q * 4;
        d[32] = __float2half(s4.x);  d[33] = __float2half(s4.y);
        d[34] = __float2half(s4.z);  d[35] = __float2half(s4.w);
#pragma unroll
        for (int j = 0; j < 4; ++j) {
            d[64 + j] = __float2half(me[j]);
            d[160 + j] = __float2half(sqrtf(fmaxf(qq[j] * inv - me[j] * me[j], 0.f) + 1e-5f));
        }
        d[96] = __float2half(mn4.x);  d[97] = __float2half(mn4.y);
        d[98] = __float2half(mn4.z);  d[99] = __float2half(mn4.w);
        d[128] = __float2half(mx4.x); d[129] = __float2half(mx4.y);
        d[130] = __float2half(mx4.z); d[131] = __float2half(mx4.w);
    }
    __syncthreads();

    float acc[32];
#pragma unroll
    for (int g = 0; g < 32; ++g) acc[g] = 0.f;
    int k20 = (p == 0) ? 0 : 16;
    const unsigned* wrow = W3h + ((size_t)(t * 3 + p) * 96 + k20) * 32;
    const unsigned* us2 = (const unsigned*)(uh + lane * 194);
    for (int k2 = k20; k2 < 96; ++k2) {
        half2_t uv = u2h(us2[k2]);
#pragma unroll
        for (int g = 0; g < 32; ++g) acc[g] = fdot2_acc(u2h(wrow[g]), uv, acc[g]);
        wrow += 32;
    }
    __syncthreads();
    {
        __half* zb = zh + p * (64 * 34) + lane * 34;
#pragma unroll
        for (int g = 0; g < 32; ++g) zb[g] = __float2half(acc[g]);
    }
    __syncthreads();
    if (tid < 64) {
        int nodec = min(base + tid, n - 1);
        int cnt = rs[nodec + 1] - rs[nodec];
        float cnt1 = fmaxf((float)cnt, 1.f);
        float logd = logf(cnt1 + 1.f);
        float avg = scal[0];
        float s1 = logd / avg, s2 = avg / logd;
        const float* b0 = post_b0 + t * 32;
        const __half* z0 = zh + tid * 34;
        const __half* z1 = zh + 64 * 34 + tid * 34;
        const __half* z2 = zh + 2 * 64 * 34 + tid * 34;
        __half* rb = rh + tid * 34;
#pragma unroll
        for (int g = 0; g < 32; ++g) {
            float r = __half2float(z0[g]) + s1 * __half2float(z1[g]) + s2 * __half2float(z2[g]) + b0[g];
            rb[g] = __float2half(fmaxf(r, 0.f));
        }
    }
    __syncthreads();
    if (tid < 128) {
        int h = __builtin_amdgcn_readfirstlane(tid >> 6);
        int l = tid & 63;
        float acc2[16];
        const float* b1 = post_b1 + t * 32 + h * 16;
#pragma unroll
        for (int j = 0; j < 16; ++j) acc2[j] = b1[j];
        const __half* rb = rh + l * 34;
        const float* w1 = w1t + (t * 32) * 32 + h * 16;
#pragma unroll
        for (int f = 0; f < 32; ++f) {
            float rv = __half2float(rb[f]);
#pragma unroll
            for (int j = 0; j < 16; ++j) acc2[j] += w1[f * 32 + j] * rv;
        }
        int node2 = base + l;
        if (node2 < n) {
            __half* yr = y1 + (size_t)node2 * 128 + t * 32 + h * 16;
#pragma unroll
            for (int j = 0; j < 16; ++j) yr[j] = __float2half(acc2[j]);
        }
    }
}

// ---------------- K7: Linear(128,128) + LN + ReLU + residual ---------------
__global__ __launch_bounds__(256) void k_final3(
    const __half* __restrict__ y1, const float* __restrict__ lwt,
    const float* __restrict__ lin_b, const float* __restrict__ ln_g,
    const float* __restrict__ ln_b, const float* __restrict__ x,
    float* __restrict__ out, int n) {
    __shared__ __half yt[64 * 130];
    __shared__ float lnbuf[64][8];
    int tid = threadIdx.x;
    int base = blockIdx.x * 64;
    for (int i = tid; i < 1024; i += 256) {
        int nl = i >> 4, q = i & 15;
        int node = min(base + nl, n - 1);
        const __half* sp = y1 + (size_t)node * 128 + q * 8;
        __half* d = yt + nl * 130 + q * 8;
#pragma unroll
        for (int j = 0; j < 8; ++j) d[j] = sp[j];
    }
    __syncthreads();
    int w = __builtin_amdgcn_readfirstlane(tid >> 6);
    int l = tid & 63;
    int j0 = w * 32;
    float acc[32];
    const float* lb = lin_b + j0;
#pragma unroll
    for (int j = 0; j < 32; ++j) acc[j] = lb[j];
    const __half* yrow = yt + l * 130;
    const float* wr = lwt + j0;
    for (int k = 0; k < 128; ++k) {
        float v = __half2float(yrow[k]);
#pragma unroll
        for (int j = 0; j < 32; ++j) acc[j] += wr[j] * v;
        wr += 128;
    }
    float s = 0.f, sq = 0.f;
#pragma unroll
    for (int j = 0; j < 32; ++j) { s += acc[j]; sq += acc[j] * acc[j]; }
    lnbuf[l][w * 2] = s;
    lnbuf[l][w * 2 + 1] = sq;
    __syncthreads();
    float S = 0.f, SQ = 0.f;
#pragma unroll
    for (int i = 0; i < 4; ++i) { S += lnbuf[l][2 * i]; SQ += lnbuf[l][2 * i + 1]; }
    float mu = S * (1.f / 128.f);
    float var = fmaxf(SQ * (1.f / 128.f) - mu * mu, 0.f);
    float rstd = rsqrtf(var + 1e-5f);
    int node = base + l;
    if (node < n) {
        const float* xr = x + (size_t)node * 128 + j0;
        float* orow = out + (size_t)node * 128 + j0;
#pragma unroll
        for (int j = 0; j < 32; ++j) {
            float o = (acc[j] - mu) * rstd * ln_g[j0 + j] + ln_b[j0 + j];
            orow[j] = xr[j] + fmaxf(o, 0.f);
        }
    }
}

extern "C" void kernel_launch(void* const* d_in, const int* in_sizes, int n_in,
                              void* d_out, int out_size, void* d_ws, size_t ws_size,
                              hipStream_t stream) {
    const float* atom_x   = (const float*)d_in[0];
    const int*   bond_x   = (const int*)d_in[1];
    const int*   aei      = (const int*)d_in[2];
    const int*   deg_hist = (const int*)d_in[3];
    const float* emb      = (const float*)d_in[4];
    const float* edge_w   = (const float*)d_in[5];
    const float* edge_b   = (const float*)d_in[6];
    const float* pre_w0   = (const float*)d_in[7];
    const float* pre_b0   = (const float*)d_in[8];
    const float* pre_w1   = (const float*)d_in[9];
    const float* pre_b1   = (const float*)d_in[10];
    const float* post_w0  = (const float*)d_in[11];
    const float* post_b0  = (const float*)d_in[12];
    const float* post_w1  = (const float*)d_in[13];
    const float* post_b1  = (const float*)d_in[14];
    const float* lin_w    = (const float*)d_in[15];
    const float* lin_b    = (const float*)d_in[16];
    const float* ln_g     = (const float*)d_in[17];
    const float* ln_b     = (const float*)d_in[18];

    int n = in_sizes[0] / H_DIM;     // 40000
    int E = in_sizes[1];             // 320000
    const int* src = aei;
    const int* dst = aei + E;

    char* ws = (char*)d_ws;
    size_t off = 0;
    auto alloc = [&](size_t bytes) {
        size_t r = off;
        off = (off + bytes + 511) & ~(size_t)511;
        return r;
    };
    float*    ctab  = (float*)(ws + alloc(5 * 128 * 4));
    float*    scal  = (float*)(ws + alloc(256));
    unsigned* W3h   = (unsigned*)(ws + alloc((size_t)4 * 3 * 96 * 32 * 4));
    float*    w1t   = (float*)(ws + alloc(4 * 32 * 32 * 4));
    float*    lwt   = (float*)(ws + alloc(128 * 128 * 4));
    float*    wab   = (float*)(ws + alloc(2 * 4 * 32 * 32 * 4));
    unsigned* w1q   = (unsigned*)(ws + alloc(2048 * 4));
    int*      cnt   = (int*)(ws + alloc((size_t)n * 4));
    int*      rs    = (int*)(ws + alloc((size_t)(n + 1) * 4));
    int*      cur   = (int*)(ws + alloc((size_t)n * 4));
    int*      bsum  = (int*)(ws + alloc(4096));
    int*      boff  = (int*)(ws + alloc(4096));
    int*      srcS  = (int*)(ws + alloc((size_t)E * 4));
    int*      bndS  = (int*)(ws + alloc((size_t)E * 4));
    float*    A     = (float*)(ws + alloc((size_t)n * 128 * 4));
    _Float16* Bh    = (_Float16*)(ws + alloc((size_t)n * 128 * 2));
    float*    stats = (float*)(ws + alloc((size_t)n * 512 * 4));
    __half*   y1    = (__half*)A;   // A dead after k_edge8

    if (off > ws_size) return;

    hipMemsetAsync(cnt, 0, (size_t)n * 4, stream);
    int nPrep = (T_TOW * 3 * 96 * 32 + 255) / 256;   // 144 blocks covers all branches
    k_prep<<<nPrep, 256, 0, stream>>>(emb, edge_w, edge_b, pre_w0, pre_b0, pre_w1, deg_hist,
                                      post_w0, post_w1, lin_w, dst, E,
                                      ctab, scal, W3h, w1t, lwt, wab, w1q, cnt);
    int nb = (n + 255) / 256;
    k_blocksum<<<nb, 256, 0, stream>>>(cnt, bsum, n);
    k_scanb<<<1, 512, 0, stream>>>(bsum, boff, nb, rs, n);
    k_scanc<<<nb, 256, 0, stream>>>(cnt, boff, rs, cur, n);
    k_bucket<<<(E + 255) / 256, 256, 0, stream>>>(src, dst, bond_x, cur, srcS, bndS, E);
    int nTiles = (n + 63) / 64;
    k_ab3<<<nTiles, 256, 0, stream>>>(atom_x, wab, A, Bh, n);
    k_edge8<<<(n + 3) / 4, 256, 0, stream>>>(A, Bh, ctab, w1q, pre_b1, rs, srcS, bndS,
                                             stats, n);
    k_post5<<<nTiles * 4, 192, 0, stream>>>(atom_x, stats, rs, scal, W3h, w1t,
                                            post_b0, post_b1, y1, n);
    k_final3<<<nTiles, 256, 0, stream>>>(y1, lwt, lin_b, ln_g, ln_b, atom_x,
                                         (float*)d_out, n);
}